// Round 1
// baseline (192.052 us; speedup 1.0000x reference)
//
#include <hip/hip_runtime.h>
#include <hip/hip_bf16.h>
#include <stdint.h>

// CKA loss via algebraic reduction:
//   HSIC_ij = ||Xi^T Xj||_F^2 - <d_i,d_j> - 2N<r_i,r_j> + N^2 t_i t_j
// where d[n]=||x_n||^2, r[n]=(x_n.s - d[n])/N, s=sum_n x_n, t=(|s|^2-sum d)/N^2.
// Heavy part: 21 bf16-MFMA GEMMs [512x4096]x[4096x512], Frobenius-reduced
// on the fly (no C materialization -> C/D layout bug-immune).

#define NPTS  4096
#define DF    512
#define ML    6
#define NPAIR 21

typedef __bf16 bf16_t;
typedef bf16_t bf16x8 __attribute__((ext_vector_type(8)));
typedef float  f32x4  __attribute__((ext_vector_type(4)));
typedef unsigned short u16;

__constant__ int c_PI[NPAIR] = {0,0,0,0,0,0, 1,1,1,1,1, 2,2,2,2, 3,3,3, 4,4, 5};
__constant__ int c_PJ[NPAIR] = {0,1,2,3,4,5, 1,2,3,4,5, 2,3,4,5, 3,4,5, 4,5, 5};

// ---- workspace layout (bytes) ----
#define OFF_XT 0u                       // 6*512*4096*2 = 25165824
#define OFF_S  25165824u                // 6*512*4      = 12288   (zeroed)
#define OFF_F  (OFF_S + 12288u)        // 21*4, pad 512          (zeroed)
#define ZERO_BYTES (12288u + 512u)
#define OFF_D  (OFF_F + 512u)          // 6*4096*4 = 98304
#define OFF_R  (OFF_D + 98304u)        // 98304
#define OFF_DD (OFF_R + 98304u)        // 256
#define OFF_RD (OFF_DD + 256u)         // 256
#define OFF_T  (OFF_RD + 256u)         // 256
// total ~25.38 MB

__device__ __forceinline__ u16 f2bf(float x) {
    union { float f; unsigned u; } v; v.f = x;
    unsigned r = v.u + 0x7fffu + ((v.u >> 16) & 1u);   // RNE
    return (u16)(r >> 16);
}

__device__ __forceinline__ void gl2lds16(const void* g, void* l) {
    __builtin_amdgcn_global_load_lds(
        (__attribute__((address_space(1))) void*)g,
        (__attribute__((address_space(3))) void*)l, 16, 0, 0);
}

// ---------------- K1: transpose + fp32->bf16 : X[l][n][d] -> Xt[l][d][n] -----
__global__ __launch_bounds__(256) void k_transpose(const float* __restrict__ X,
                                                   u16* __restrict__ Xt) {
    __shared__ float tile[64][65];
    int l = blockIdx.z, nt = blockIdx.x, dt = blockIdx.y;
    int n0 = nt * 64, d0 = dt * 64;
    int t = threadIdx.x, c = t & 63, rq = t >> 6;         // c: 0..63, rq: 0..3
    const float* src = X + ((size_t)l * NPTS + n0) * DF + d0;
#pragma unroll
    for (int s = 0; s < 16; ++s) {
        int r = rq * 16 + s;
        tile[r][c] = src[(size_t)r * DF + c];
    }
    __syncthreads();
    u16* dst = Xt + ((size_t)l * DF + d0) * NPTS + n0;
#pragma unroll
    for (int s = 0; s < 16; ++s) {
        int dcol = rq * 16 + s;                            // d index = Xt row
        dst[(size_t)dcol * NPTS + c] = f2bf(tile[c][dcol]);
    }
}

// ---------------- K2: column sums s[l][d] (fp32, atomic over row chunks) -----
__global__ __launch_bounds__(512) void k_colsum(const float* __restrict__ X,
                                                float* __restrict__ s) {
    int l = blockIdx.y;
    int d = threadIdx.x;                                   // 0..511
    const float* src = X + ((size_t)l * NPTS + blockIdx.x * 128) * DF + d;
    float acc = 0.f;
#pragma unroll 4
    for (int r = 0; r < 128; ++r) acc += src[(size_t)r * DF];
    atomicAdd(&s[l * DF + d], acc);
}

// ---------------- K3: row stats d[n], r[n] (one wave per row) ----------------
__global__ __launch_bounds__(256) void k_rowstats(const float* __restrict__ X,
                                                  const float* __restrict__ s,
                                                  float* __restrict__ dv,
                                                  float* __restrict__ rv) {
    int t = threadIdx.x, wave = t >> 6, lane = t & 63;
    int gw = blockIdx.x * 4 + wave;                        // = l*4096 + n
    int l = gw >> 12;
    const float4* row = (const float4*)(X + (size_t)gw * DF);
    const float4* sv  = (const float4*)(s + l * DF);
    float sum2 = 0.f, dots = 0.f;
#pragma unroll
    for (int q = 0; q < 2; ++q) {
        float4 x = row[lane * 2 + q];
        float4 sf = sv[lane * 2 + q];
        sum2 += x.x * x.x + x.y * x.y + x.z * x.z + x.w * x.w;
        dots += x.x * sf.x + x.y * sf.y + x.z * sf.z + x.w * sf.w;
    }
    for (int off = 32; off; off >>= 1) {
        sum2 += __shfl_down(sum2, off);
        dots += __shfl_down(dots, off);
    }
    if (lane == 0) {
        dv[gw] = sum2;
        rv[gw] = (dots - sum2) * (1.0f / (float)NPTS);
    }
}

// ---------------- K4: pair dots <d_i,d_j>, <r_i,r_j>, and t_i ----------------
__global__ __launch_bounds__(256) void k_pairdots(const float* __restrict__ dv,
                                                  const float* __restrict__ rv,
                                                  const float* __restrict__ s,
                                                  float* __restrict__ ddot,
                                                  float* __restrict__ rdot,
                                                  float* __restrict__ tb) {
    int p = blockIdx.x, i = c_PI[p], j = c_PJ[p];
    int t = threadIdx.x;
    float dd = 0.f, rr = 0.f, sd = 0.f, ss = 0.f;
    for (int n = t; n < NPTS; n += 256) {
        float di = dv[i * NPTS + n];
        dd += di * dv[j * NPTS + n];
        rr += rv[i * NPTS + n] * rv[j * NPTS + n];
        sd += di;
    }
    for (int c = t; c < DF; c += 256) { float v = s[i * DF + c]; ss += v * v; }
    __shared__ float4 red[256];
    red[t] = make_float4(dd, rr, sd, ss);
    __syncthreads();
    for (int h = 128; h > 0; h >>= 1) {
        if (t < h) {
            float4 a = red[t], b = red[t + h];
            red[t] = make_float4(a.x + b.x, a.y + b.y, a.z + b.z, a.w + b.w);
        }
        __syncthreads();
    }
    if (t == 0) {
        ddot[p] = red[0].x;
        rdot[p] = red[0].y;
        if (i == j)
            tb[i] = (red[0].w - red[0].z) * (1.0f / ((float)NPTS * (float)NPTS));
    }
}

// ---------------- K5: bf16 MFMA GEMM + Frobenius reduce ----------------------
// grid (16, 21): blockIdx.x = 4x4 tile of the 512x512 C, blockIdx.y = pair.
// 128x128 tile, 4 waves each 64x64 (4x4 of 16x16x32 MFMA), BK=32.
__global__ __launch_bounds__(256) void k_gemm_frob(const u16* __restrict__ Xt,
                                                   float* __restrict__ F) {
    int p = blockIdx.y;
    int aBase = (blockIdx.x & 3) * 128;
    int bBase = (blockIdx.x >> 2) * 128;
    const u16* A = Xt + ((size_t)(c_PI[p] * DF + aBase)) * NPTS;
    const u16* B = Xt + ((size_t)(c_PJ[p] * DF + bBase)) * NPTS;

    __shared__ __align__(16) u16 As[128 * 32];
    __shared__ __align__(16) u16 Bs[128 * 32];

    int t = threadIdx.x, wave = t >> 6, lane = t & 63;
    int rl = lane >> 2, g = lane & 3;          // staging: row-in-16, 16B group
    int wr = (wave >> 1) * 64, wc = (wave & 1) * 64;
    int row16 = lane & 15, quad = lane >> 4;   // MFMA fragment indices

    f32x4 acc[4][4];
#pragma unroll
    for (int mi = 0; mi < 4; ++mi)
#pragma unroll
        for (int ni = 0; ni < 4; ++ni) acc[mi][ni] = (f32x4)0.0f;

    for (int k0 = 0; k0 < NPTS; k0 += 32) {
        __syncthreads();   // previous iter's ds_reads done before DMA overwrite
#pragma unroll
        for (int is = 0; is < 2; ++is) {
            int rbase = is * 64 + wave * 16;               // wave-uniform
            int r = rbase + rl;
            int gs = g ^ ((r >> 1) & 3);                   // XOR swizzle
            gl2lds16(A + (size_t)r * NPTS + k0 + gs * 8, &As[rbase * 32]);
            gl2lds16(B + (size_t)r * NPTS + k0 + gs * 8, &Bs[rbase * 32]);
        }
        __syncthreads();   // vmcnt(0) drained at barrier -> LDS valid

        bf16x8 af[4], bf[4];
#pragma unroll
        for (int mi = 0; mi < 4; ++mi) {
            int row = wr + mi * 16 + row16;
            int gg = quad ^ ((row >> 1) & 3);
            af[mi] = *(const bf16x8*)&As[row * 32 + gg * 8];
        }
#pragma unroll
        for (int ni = 0; ni < 4; ++ni) {
            int row = wc + ni * 16 + row16;
            int gg = quad ^ ((row >> 1) & 3);
            bf[ni] = *(const bf16x8*)&Bs[row * 32 + gg * 8];
        }
#pragma unroll
        for (int mi = 0; mi < 4; ++mi)
#pragma unroll
            for (int ni = 0; ni < 4; ++ni)
                acc[mi][ni] = __builtin_amdgcn_mfma_f32_16x16x32_bf16(
                    af[mi], bf[ni], acc[mi][ni], 0, 0, 0);
    }

    // Frobenius reduce (layout-agnostic: every acc element counted once)
    float local = 0.f;
#pragma unroll
    for (int mi = 0; mi < 4; ++mi)
#pragma unroll
        for (int ni = 0; ni < 4; ++ni)
#pragma unroll
            for (int e = 0; e < 4; ++e)
                local += acc[mi][ni][e] * acc[mi][ni][e];
    for (int off = 32; off; off >>= 1) local += __shfl_down(local, off);
    __shared__ float wsum[4];
    if (lane == 0) wsum[wave] = local;
    __syncthreads();
    if (t == 0) atomicAdd(&F[p], wsum[0] + wsum[1] + wsum[2] + wsum[3]);
}

// ---------------- K6: finalize -> hsic_visual (36) + l (1) -------------------
__global__ __launch_bounds__(64) void k_finalize(const float* __restrict__ F,
                                                 const float* __restrict__ ddot,
                                                 const float* __restrict__ rdot,
                                                 const float* __restrict__ tb,
                                                 float* __restrict__ out) {
    __shared__ double hs[ML][ML];
    __shared__ float cka[ML][ML];
    int t = threadIdx.x;
    if (t < NPAIR) {
        int i = c_PI[t], j = c_PJ[t];
        double v = (double)F[t] - (double)ddot[t]
                 - 2.0 * (double)NPTS * (double)rdot[t]
                 + (double)NPTS * (double)NPTS * (double)tb[i] * (double)tb[j];
        hs[i][j] = v; hs[j][i] = v;
    }
    __syncthreads();
    if (t < ML * ML) {
        int i = t / ML, j = t % ML;
        float v;
        if (i == j) v = 1.0f;
        else v = (float)(fabs(hs[i][j]) / sqrt(hs[i][i] * hs[j][j] + 1e-6));
        cka[i][j] = v;
        out[t] = v;
    }
    __syncthreads();
    if (t == 0) {
        float l = 0.f;
        for (int i = 1; i < ML; ++i)
            for (int j = 0; j < i; ++j) l += cka[i][j];   // cka >= 0
        out[ML * ML] = l;
    }
}

extern "C" void kernel_launch(void* const* d_in, const int* in_sizes, int n_in,
                              void* d_out, int out_size, void* d_ws, size_t ws_size,
                              hipStream_t stream) {
    (void)in_sizes; (void)n_in; (void)out_size; (void)ws_size;
    const float* X = (const float*)d_in[0];
    float* out = (float*)d_out;
    char* ws = (char*)d_ws;
    u16*   Xt = (u16*)(ws + OFF_XT);
    float* s  = (float*)(ws + OFF_S);
    float* F  = (float*)(ws + OFF_F);
    float* dv = (float*)(ws + OFF_D);
    float* rv = (float*)(ws + OFF_R);
    float* dd = (float*)(ws + OFF_DD);
    float* rd = (float*)(ws + OFF_RD);
    float* tb = (float*)(ws + OFF_T);

    hipMemsetAsync(ws + OFF_S, 0, ZERO_BYTES, stream);     // zero s + F

    hipLaunchKernelGGL(k_transpose, dim3(64, 8, 6), dim3(256), 0, stream, X, Xt);
    hipLaunchKernelGGL(k_colsum,    dim3(32, 6),    dim3(512), 0, stream, X, s);
    hipLaunchKernelGGL(k_rowstats,  dim3(6144),     dim3(256), 0, stream, X, s, dv, rv);
    hipLaunchKernelGGL(k_pairdots,  dim3(NPAIR),    dim3(256), 0, stream, dv, rv, s, dd, rd, tb);
    hipLaunchKernelGGL(k_gemm_frob, dim3(16, NPAIR),dim3(256), 0, stream, Xt, F);
    hipLaunchKernelGGL(k_finalize,  dim3(1),        dim3(64),  0, stream, F, dd, rd, tb, out);
}

// Round 2
// 169.331 us; speedup vs baseline: 1.1342x; 1.1342x over previous
//
#include <hip/hip_runtime.h>
#include <hip/hip_bf16.h>
#include <stdint.h>

// CKA loss via algebraic reduction:
//   HSIC_ij = ||Xi^T Xj||_F^2 - <d_i,d_j> - 2N<r_i,r_j> + N^2 t_i t_j
// where d[n]=||x_n||^2, r[n]=(x_n.s - d[n])/N, s=sum_n x_n, t=(|s|^2-sum d)/N^2.
// Heavy part: 21 bf16-MFMA GEMMs [512x4096]x[4096x512], Frobenius-reduced
// on the fly (no C materialization -> C/D layout bug-immune).
//
// R2: split-K x4 on the GEMM (336 -> 1344 blocks; R1 showed MfmaUtil 21% /
// Occupancy 12% -> latency-bound on wave count). Column sums fused into the
// transpose (k_colsum removed).

#define NPTS  4096
#define DF    512
#define ML    6
#define NPAIR 21
#define KSPLIT 4
#define KCHUNK (NPTS / KSPLIT)

typedef __bf16 bf16_t;
typedef bf16_t bf16x8 __attribute__((ext_vector_type(8)));
typedef float  f32x4  __attribute__((ext_vector_type(4)));
typedef unsigned short u16;

__constant__ int c_PI[NPAIR] = {0,0,0,0,0,0, 1,1,1,1,1, 2,2,2,2, 3,3,3, 4,4, 5};
__constant__ int c_PJ[NPAIR] = {0,1,2,3,4,5, 1,2,3,4,5, 2,3,4,5, 3,4,5, 4,5, 5};

// ---- workspace layout (bytes) ----
#define OFF_XT 0u                       // 6*512*4096*2 = 25165824
#define OFF_S  25165824u                // 6*512*4      = 12288   (zeroed)
#define OFF_F  (OFF_S + 12288u)        // 21*4, pad 512          (zeroed)
#define ZERO_BYTES (12288u + 512u)
#define OFF_D  (OFF_F + 512u)          // 6*4096*4 = 98304
#define OFF_R  (OFF_D + 98304u)        // 98304
#define OFF_DD (OFF_R + 98304u)        // 256
#define OFF_RD (OFF_DD + 256u)         // 256
#define OFF_T  (OFF_RD + 256u)         // 256
// total ~25.38 MB

__device__ __forceinline__ u16 f2bf(float x) {
    union { float f; unsigned u; } v; v.f = x;
    unsigned r = v.u + 0x7fffu + ((v.u >> 16) & 1u);   // RNE
    return (u16)(r >> 16);
}

__device__ __forceinline__ void gl2lds16(const void* g, void* l) {
    __builtin_amdgcn_global_load_lds(
        (__attribute__((address_space(1))) void*)g,
        (__attribute__((address_space(3))) void*)l, 16, 0, 0);
}

// ------- K1: transpose + fp32->bf16 + fused column sums ----------------------
// X[l][n][d] -> Xt[l][d][n]; s[l][d] += partial column sums (atomics).
__global__ __launch_bounds__(256) void k_transpose(const float* __restrict__ X,
                                                   u16* __restrict__ Xt,
                                                   float* __restrict__ s) {
    __shared__ float tile[64][65];
    int l = blockIdx.z, nt = blockIdx.x, dt = blockIdx.y;
    int n0 = nt * 64, d0 = dt * 64;
    int t = threadIdx.x, c = t & 63, rq = t >> 6;         // c: 0..63, rq: 0..3
    const float* src = X + ((size_t)l * NPTS + n0) * DF + d0;
    float csum = 0.f;                                      // column d0+c partial
#pragma unroll
    for (int i = 0; i < 16; ++i) {
        int r = rq * 16 + i;
        float v = src[(size_t)r * DF + c];
        tile[r][c] = v;
        csum += v;
    }
    atomicAdd(&s[l * DF + d0 + c], csum);
    __syncthreads();
    u16* dst = Xt + ((size_t)l * DF + d0) * NPTS + n0;
#pragma unroll
    for (int i = 0; i < 16; ++i) {
        int dcol = rq * 16 + i;                            // d index = Xt row
        dst[(size_t)dcol * NPTS + c] = f2bf(tile[c][dcol]);
    }
}

// ---------------- K3: row stats d[n], r[n] (one wave per row) ----------------
__global__ __launch_bounds__(256) void k_rowstats(const float* __restrict__ X,
                                                  const float* __restrict__ s,
                                                  float* __restrict__ dv,
                                                  float* __restrict__ rv) {
    int t = threadIdx.x, wave = t >> 6, lane = t & 63;
    int gw = blockIdx.x * 4 + wave;                        // = l*4096 + n
    int l = gw >> 12;
    const float4* row = (const float4*)(X + (size_t)gw * DF);
    const float4* sv  = (const float4*)(s + l * DF);
    float sum2 = 0.f, dots = 0.f;
#pragma unroll
    for (int q = 0; q < 2; ++q) {
        float4 x = row[lane * 2 + q];
        float4 sf = sv[lane * 2 + q];
        sum2 += x.x * x.x + x.y * x.y + x.z * x.z + x.w * x.w;
        dots += x.x * sf.x + x.y * sf.y + x.z * sf.z + x.w * sf.w;
    }
    for (int off = 32; off; off >>= 1) {
        sum2 += __shfl_down(sum2, off);
        dots += __shfl_down(dots, off);
    }
    if (lane == 0) {
        dv[gw] = sum2;
        rv[gw] = (dots - sum2) * (1.0f / (float)NPTS);
    }
}

// ---------------- K4: pair dots <d_i,d_j>, <r_i,r_j>, and t_i ----------------
__global__ __launch_bounds__(256) void k_pairdots(const float* __restrict__ dv,
                                                  const float* __restrict__ rv,
                                                  const float* __restrict__ s,
                                                  float* __restrict__ ddot,
                                                  float* __restrict__ rdot,
                                                  float* __restrict__ tb) {
    int p = blockIdx.x, i = c_PI[p], j = c_PJ[p];
    int t = threadIdx.x;
    float dd = 0.f, rr = 0.f, sd = 0.f, ss = 0.f;
    for (int n = t; n < NPTS; n += 256) {
        float di = dv[i * NPTS + n];
        dd += di * dv[j * NPTS + n];
        rr += rv[i * NPTS + n] * rv[j * NPTS + n];
        sd += di;
    }
    for (int c = t; c < DF; c += 256) { float v = s[i * DF + c]; ss += v * v; }
    __shared__ float4 red[256];
    red[t] = make_float4(dd, rr, sd, ss);
    __syncthreads();
    for (int h = 128; h > 0; h >>= 1) {
        if (t < h) {
            float4 a = red[t], b = red[t + h];
            red[t] = make_float4(a.x + b.x, a.y + b.y, a.z + b.z, a.w + b.w);
        }
        __syncthreads();
    }
    if (t == 0) {
        ddot[p] = red[0].x;
        rdot[p] = red[0].y;
        if (i == j)
            tb[i] = (red[0].w - red[0].z) * (1.0f / ((float)NPTS * (float)NPTS));
    }
}

// ---------------- K5: bf16 MFMA GEMM + Frobenius reduce (split-K) ------------
// grid (16, 21, 4): x = 4x4 tile of 512x512 C, y = pair, z = K-chunk of 1024.
// 128x128 tile, 4 waves each 64x64 (4x4 of 16x16x32 MFMA), BK=32.
__global__ __launch_bounds__(256) void k_gemm_frob(const u16* __restrict__ Xt,
                                                   float* __restrict__ F) {
    int p = blockIdx.y;
    int aBase = (blockIdx.x & 3) * 128;
    int bBase = (blockIdx.x >> 2) * 128;
    int kLo = blockIdx.z * KCHUNK, kHi = kLo + KCHUNK;
    const u16* A = Xt + ((size_t)(c_PI[p] * DF + aBase)) * NPTS;
    const u16* B = Xt + ((size_t)(c_PJ[p] * DF + bBase)) * NPTS;

    __shared__ __align__(16) u16 As[128 * 32];
    __shared__ __align__(16) u16 Bs[128 * 32];

    int t = threadIdx.x, wave = t >> 6, lane = t & 63;
    int rl = lane >> 2, g = lane & 3;          // staging: row-in-16, 16B group
    int wr = (wave >> 1) * 64, wc = (wave & 1) * 64;
    int row16 = lane & 15, quad = lane >> 4;   // MFMA fragment indices

    f32x4 acc[4][4];
#pragma unroll
    for (int mi = 0; mi < 4; ++mi)
#pragma unroll
        for (int ni = 0; ni < 4; ++ni) acc[mi][ni] = (f32x4)0.0f;

    for (int k0 = kLo; k0 < kHi; k0 += 32) {
        __syncthreads();   // previous iter's ds_reads done before DMA overwrite
#pragma unroll
        for (int is = 0; is < 2; ++is) {
            int rbase = is * 64 + wave * 16;               // wave-uniform
            int r = rbase + rl;
            int gs = g ^ ((r >> 1) & 3);                   // XOR swizzle
            gl2lds16(A + (size_t)r * NPTS + k0 + gs * 8, &As[rbase * 32]);
            gl2lds16(B + (size_t)r * NPTS + k0 + gs * 8, &Bs[rbase * 32]);
        }
        __syncthreads();   // vmcnt(0) drained at barrier -> LDS valid

        bf16x8 af[4], bf[4];
#pragma unroll
        for (int mi = 0; mi < 4; ++mi) {
            int row = wr + mi * 16 + row16;
            int gg = quad ^ ((row >> 1) & 3);
            af[mi] = *(const bf16x8*)&As[row * 32 + gg * 8];
        }
#pragma unroll
        for (int ni = 0; ni < 4; ++ni) {
            int row = wc + ni * 16 + row16;
            int gg = quad ^ ((row >> 1) & 3);
            bf[ni] = *(const bf16x8*)&Bs[row * 32 + gg * 8];
        }
#pragma unroll
        for (int mi = 0; mi < 4; ++mi)
#pragma unroll
            for (int ni = 0; ni < 4; ++ni)
                acc[mi][ni] = __builtin_amdgcn_mfma_f32_16x16x32_bf16(
                    af[mi], bf[ni], acc[mi][ni], 0, 0, 0);
    }

    // Frobenius reduce (layout-agnostic: every acc element counted once)
    float local = 0.f;
#pragma unroll
    for (int mi = 0; mi < 4; ++mi)
#pragma unroll
        for (int ni = 0; ni < 4; ++ni)
#pragma unroll
            for (int e = 0; e < 4; ++e)
                local += acc[mi][ni][e] * acc[mi][ni][e];
    for (int off = 32; off; off >>= 1) local += __shfl_down(local, off);
    __shared__ float wsum[4];
    if (lane == 0) wsum[wave] = local;
    __syncthreads();
    if (t == 0) atomicAdd(&F[p], wsum[0] + wsum[1] + wsum[2] + wsum[3]);
}

// ---------------- K6: finalize -> hsic_visual (36) + l (1) -------------------
__global__ __launch_bounds__(64) void k_finalize(const float* __restrict__ F,
                                                 const float* __restrict__ ddot,
                                                 const float* __restrict__ rdot,
                                                 const float* __restrict__ tb,
                                                 float* __restrict__ out) {
    __shared__ double hs[ML][ML];
    __shared__ float cka[ML][ML];
    int t = threadIdx.x;
    if (t < NPAIR) {
        int i = c_PI[t], j = c_PJ[t];
        double v = (double)F[t] - (double)ddot[t]
                 - 2.0 * (double)NPTS * (double)rdot[t]
                 + (double)NPTS * (double)NPTS * (double)tb[i] * (double)tb[j];
        hs[i][j] = v; hs[j][i] = v;
    }
    __syncthreads();
    if (t < ML * ML) {
        int i = t / ML, j = t % ML;
        float v;
        if (i == j) v = 1.0f;
        else v = (float)(fabs(hs[i][j]) / sqrt(hs[i][i] * hs[j][j] + 1e-6));
        cka[i][j] = v;
        out[t] = v;
    }
    __syncthreads();
    if (t == 0) {
        float l = 0.f;
        for (int i = 1; i < ML; ++i)
            for (int j = 0; j < i; ++j) l += cka[i][j];   // cka >= 0
        out[ML * ML] = l;
    }
}

extern "C" void kernel_launch(void* const* d_in, const int* in_sizes, int n_in,
                              void* d_out, int out_size, void* d_ws, size_t ws_size,
                              hipStream_t stream) {
    (void)in_sizes; (void)n_in; (void)out_size; (void)ws_size;
    const float* X = (const float*)d_in[0];
    float* out = (float*)d_out;
    char* ws = (char*)d_ws;
    u16*   Xt = (u16*)(ws + OFF_XT);
    float* s  = (float*)(ws + OFF_S);
    float* F  = (float*)(ws + OFF_F);
    float* dv = (float*)(ws + OFF_D);
    float* rv = (float*)(ws + OFF_R);
    float* dd = (float*)(ws + OFF_DD);
    float* rd = (float*)(ws + OFF_RD);
    float* tb = (float*)(ws + OFF_T);

    hipMemsetAsync(ws + OFF_S, 0, ZERO_BYTES, stream);     // zero s + F

    hipLaunchKernelGGL(k_transpose, dim3(64, 8, 6), dim3(256), 0, stream, X, Xt, s);
    hipLaunchKernelGGL(k_rowstats,  dim3(6144),     dim3(256), 0, stream, X, s, dv, rv);
    hipLaunchKernelGGL(k_pairdots,  dim3(NPAIR),    dim3(256), 0, stream, dv, rv, s, dd, rd, tb);
    hipLaunchKernelGGL(k_gemm_frob, dim3(16, NPAIR, KSPLIT), dim3(256), 0, stream, Xt, F);
    hipLaunchKernelGGL(k_finalize,  dim3(1),        dim3(64),  0, stream, F, dd, rd, tb, out);
}

// Round 3
// 160.795 us; speedup vs baseline: 1.1944x; 1.0531x over previous
//
#include <hip/hip_runtime.h>
#include <hip/hip_bf16.h>
#include <stdint.h>

// CKA loss via algebraic reduction:
//   HSIC_ij = ||Xi^T Xj||_F^2 - <d_i,d_j> - 2N<r_i,r_j> + N^2 t_i t_j
// Heavy part: 21 bf16-MFMA GEMMs [512x4096]x[4096x512], Frobenius-reduced.
//
// R3: GEMM is LDS-read-BW-bound (R2: 78 B/cyc/CU ~= 92% of ds_read_b128
// ceiling; MfmaUtil 27% == LDS-fed rate). Wave tile 64x64 -> 64x128
// (4x8 acc, 128 AGPR) cuts LDS bytes/FLOP 1.33x. Block 128x256, KSPLIT=8.
// Transpose vectorized (float4 in, ushort4 out).

#define NPTS  4096
#define DF    512
#define ML    6
#define NPAIR 21
#define KSPLIT 8
#define KCHUNK (NPTS / KSPLIT)   // 512

typedef __bf16 bf16_t;
typedef bf16_t bf16x8 __attribute__((ext_vector_type(8)));
typedef float  f32x4  __attribute__((ext_vector_type(4)));
typedef unsigned short u16;

__constant__ int c_PI[NPAIR] = {0,0,0,0,0,0, 1,1,1,1,1, 2,2,2,2, 3,3,3, 4,4, 5};
__constant__ int c_PJ[NPAIR] = {0,1,2,3,4,5, 1,2,3,4,5, 2,3,4,5, 3,4,5, 4,5, 5};

// ---- workspace layout (bytes) ----
#define OFF_XT 0u                       // 6*512*4096*2 = 25165824
#define OFF_S  25165824u                // 6*512*4      = 12288   (zeroed)
#define OFF_F  (OFF_S + 12288u)        // 21*4, pad 512          (zeroed)
#define ZERO_BYTES (12288u + 512u)
#define OFF_D  (OFF_F + 512u)          // 6*4096*4 = 98304
#define OFF_R  (OFF_D + 98304u)        // 98304
#define OFF_DD (OFF_R + 98304u)        // 256
#define OFF_RD (OFF_DD + 256u)         // 256
#define OFF_T  (OFF_RD + 256u)         // 256

__device__ __forceinline__ u16 f2bf(float x) {
    union { float f; unsigned u; } v; v.f = x;
    unsigned r = v.u + 0x7fffu + ((v.u >> 16) & 1u);   // RNE
    return (u16)(r >> 16);
}

__device__ __forceinline__ void gl2lds16(const void* g, void* l) {
    __builtin_amdgcn_global_load_lds(
        (__attribute__((address_space(1))) void*)g,
        (__attribute__((address_space(3))) void*)l, 16, 0, 0);
}

// ------- K1: transpose + fp32->bf16 + fused column sums ----------------------
// X[l][n][d] -> Xt[l][d][n]; s[l][d] += column-sum partials (1 atomic/col/blk).
__global__ __launch_bounds__(256) void k_transpose(const float* __restrict__ X,
                                                   u16* __restrict__ Xt,
                                                   float* __restrict__ s) {
    __shared__ float tile[64][68];                         // float4-aligned pad
    int l = blockIdx.z, n0 = blockIdx.x * 64, d0 = blockIdx.y * 64;
    int t = threadIdx.x;
    int q = t & 15, r = t >> 4;                            // 16 float4-cols x 16 rows
    const float4* src = (const float4*)(X + ((size_t)l * NPTS + n0) * DF + d0);
#pragma unroll
    for (int pp = 0; pp < 4; ++pp) {
        int rr = r + 16 * pp;
        float4 v = src[(size_t)rr * (DF / 4) + q];
        *(float4*)&tile[rr][q * 4] = v;
    }
    __syncthreads();
    if (t < 64) {                                          // column sums (n-dir)
        float cs = 0.f;
#pragma unroll
        for (int n = 0; n < 64; ++n) cs += tile[n][t];
        atomicAdd(&s[l * DF + d0 + t], cs);
    }
    int dcol = t >> 2, h = t & 3;                          // write: 4 ushort4/thread
    u16* dst = Xt + ((size_t)(l * DF + d0 + dcol)) * NPTS + n0;
#pragma unroll
    for (int w = 0; w < 4; ++w) {
        int nb = w * 16 + h * 4;
        ushort4 o;
        o.x = f2bf(tile[nb + 0][dcol]);
        o.y = f2bf(tile[nb + 1][dcol]);
        o.z = f2bf(tile[nb + 2][dcol]);
        o.w = f2bf(tile[nb + 3][dcol]);
        *(ushort4*)(dst + nb) = o;
    }
}

// ---------------- K3: row stats d[n], r[n] (one wave per row) ----------------
__global__ __launch_bounds__(256) void k_rowstats(const float* __restrict__ X,
                                                  const float* __restrict__ s,
                                                  float* __restrict__ dv,
                                                  float* __restrict__ rv) {
    int t = threadIdx.x, wave = t >> 6, lane = t & 63;
    int gw = blockIdx.x * 4 + wave;                        // = l*4096 + n
    int l = gw >> 12;
    const float4* row = (const float4*)(X + (size_t)gw * DF);
    const float4* sv  = (const float4*)(s + l * DF);
    float sum2 = 0.f, dots = 0.f;
#pragma unroll
    for (int q = 0; q < 2; ++q) {
        float4 x = row[lane * 2 + q];
        float4 sf = sv[lane * 2 + q];
        sum2 += x.x * x.x + x.y * x.y + x.z * x.z + x.w * x.w;
        dots += x.x * sf.x + x.y * sf.y + x.z * sf.z + x.w * sf.w;
    }
    for (int off = 32; off; off >>= 1) {
        sum2 += __shfl_down(sum2, off);
        dots += __shfl_down(dots, off);
    }
    if (lane == 0) {
        dv[gw] = sum2;
        rv[gw] = (dots - sum2) * (1.0f / (float)NPTS);
    }
}

// ---------------- K4: pair dots <d_i,d_j>, <r_i,r_j>, and t_i ----------------
__global__ __launch_bounds__(256) void k_pairdots(const float* __restrict__ dv,
                                                  const float* __restrict__ rv,
                                                  const float* __restrict__ s,
                                                  float* __restrict__ ddot,
                                                  float* __restrict__ rdot,
                                                  float* __restrict__ tb) {
    int p = blockIdx.x, i = c_PI[p], j = c_PJ[p];
    int t = threadIdx.x;
    float dd = 0.f, rr = 0.f, sd = 0.f, ss = 0.f;
    for (int n = t; n < NPTS; n += 256) {
        float di = dv[i * NPTS + n];
        dd += di * dv[j * NPTS + n];
        rr += rv[i * NPTS + n] * rv[j * NPTS + n];
        sd += di;
    }
    for (int c = t; c < DF; c += 256) { float v = s[i * DF + c]; ss += v * v; }
    __shared__ float4 red[256];
    red[t] = make_float4(dd, rr, sd, ss);
    __syncthreads();
    for (int h = 128; h > 0; h >>= 1) {
        if (t < h) {
            float4 a = red[t], b = red[t + h];
            red[t] = make_float4(a.x + b.x, a.y + b.y, a.z + b.z, a.w + b.w);
        }
        __syncthreads();
    }
    if (t == 0) {
        ddot[p] = red[0].x;
        rdot[p] = red[0].y;
        if (i == j)
            tb[i] = (red[0].w - red[0].z) * (1.0f / ((float)NPTS * (float)NPTS));
    }
}

// ---------------- K5: bf16 MFMA GEMM + Frobenius reduce (split-K) ------------
// grid (8, 21, 8): x = (mi 4)x(nj 2) tile of 512x512 C, y = pair, z = K/512.
// Block 128x256, 4 waves; wave tile 64x128 (4x8 of 16x16x32 MFMA), BK=32.
__global__ __launch_bounds__(256, 2) void k_gemm_frob(const u16* __restrict__ Xt,
                                                      float* __restrict__ F) {
    int p = blockIdx.y;
    int aBase = (blockIdx.x & 3) * 128;
    int bBase = (blockIdx.x >> 2) * 256;
    int kLo = blockIdx.z * KCHUNK, kHi = kLo + KCHUNK;
    const u16* A = Xt + ((size_t)(c_PI[p] * DF + aBase)) * NPTS;
    const u16* B = Xt + ((size_t)(c_PJ[p] * DF + bBase)) * NPTS;

    __shared__ __align__(16) u16 As[128 * 32];             //  8 KB
    __shared__ __align__(16) u16 Bs[256 * 32];             // 16 KB

    int t = threadIdx.x, wave = t >> 6, lane = t & 63;
    int rl = lane >> 2, g = lane & 3;          // staging: row-in-16, 16B group
    int wr = (wave >> 1) * 64, wc = (wave & 1) * 128;
    int row16 = lane & 15, quad = lane >> 4;   // MFMA fragment indices

    f32x4 acc[4][8];
#pragma unroll
    for (int mi = 0; mi < 4; ++mi)
#pragma unroll
        for (int ni = 0; ni < 8; ++ni) acc[mi][ni] = (f32x4)0.0f;

    for (int k0 = kLo; k0 < kHi; k0 += 32) {
        __syncthreads();   // previous iter's ds_reads done before DMA overwrite
#pragma unroll
        for (int is = 0; is < 2; ++is) {                   // A: 128 rows
            int rbase = is * 64 + wave * 16;               // wave-uniform
            int r = rbase + rl;
            int gs = g ^ ((r >> 1) & 3);                   // XOR swizzle
            gl2lds16(A + (size_t)r * NPTS + k0 + gs * 8, &As[rbase * 32]);
        }
#pragma unroll
        for (int is = 0; is < 4; ++is) {                   // B: 256 rows
            int rbase = is * 64 + wave * 16;
            int r = rbase + rl;
            int gs = g ^ ((r >> 1) & 3);
            gl2lds16(B + (size_t)r * NPTS + k0 + gs * 8, &Bs[rbase * 32]);
        }
        __syncthreads();   // vmcnt(0) drained at barrier -> LDS valid

        bf16x8 af[4], bf[8];
#pragma unroll
        for (int mi = 0; mi < 4; ++mi) {
            int row = wr + mi * 16 + row16;
            int gg = quad ^ ((row >> 1) & 3);
            af[mi] = *(const bf16x8*)&As[row * 32 + gg * 8];
        }
#pragma unroll
        for (int ni = 0; ni < 8; ++ni) {
            int row = wc + ni * 16 + row16;
            int gg = quad ^ ((row >> 1) & 3);
            bf[ni] = *(const bf16x8*)&Bs[row * 32 + gg * 8];
        }
#pragma unroll
        for (int mi = 0; mi < 4; ++mi)
#pragma unroll
            for (int ni = 0; ni < 8; ++ni)
                acc[mi][ni] = __builtin_amdgcn_mfma_f32_16x16x32_bf16(
                    af[mi], bf[ni], acc[mi][ni], 0, 0, 0);
    }

    // Frobenius reduce (layout-agnostic: every acc element counted once)
    float local = 0.f;
#pragma unroll
    for (int mi = 0; mi < 4; ++mi)
#pragma unroll
        for (int ni = 0; ni < 8; ++ni)
#pragma unroll
            for (int e = 0; e < 4; ++e)
                local += acc[mi][ni][e] * acc[mi][ni][e];
    for (int off = 32; off; off >>= 1) local += __shfl_down(local, off);
    __shared__ float wsum[4];
    if (lane == 0) wsum[wave] = local;
    __syncthreads();
    if (t == 0) atomicAdd(&F[p], wsum[0] + wsum[1] + wsum[2] + wsum[3]);
}

// ---------------- K6: finalize -> hsic_visual (36) + l (1) -------------------
__global__ __launch_bounds__(64) void k_finalize(const float* __restrict__ F,
                                                 const float* __restrict__ ddot,
                                                 const float* __restrict__ rdot,
                                                 const float* __restrict__ tb,
                                                 float* __restrict__ out) {
    __shared__ double hs[ML][ML];
    __shared__ float cka[ML][ML];
    int t = threadIdx.x;
    if (t < NPAIR) {
        int i = c_PI[t], j = c_PJ[t];
        double v = (double)F[t] - (double)ddot[t]
                 - 2.0 * (double)NPTS * (double)rdot[t]
                 + (double)NPTS * (double)NPTS * (double)tb[i] * (double)tb[j];
        hs[i][j] = v; hs[j][i] = v;
    }
    __syncthreads();
    if (t < ML * ML) {
        int i = t / ML, j = t % ML;
        float v;
        if (i == j) v = 1.0f;
        else v = (float)(fabs(hs[i][j]) / sqrt(hs[i][i] * hs[j][j] + 1e-6));
        cka[i][j] = v;
        out[t] = v;
    }
    __syncthreads();
    if (t == 0) {
        float l = 0.f;
        for (int i = 1; i < ML; ++i)
            for (int j = 0; j < i; ++j) l += cka[i][j];   // cka >= 0
        out[ML * ML] = l;
    }
}

extern "C" void kernel_launch(void* const* d_in, const int* in_sizes, int n_in,
                              void* d_out, int out_size, void* d_ws, size_t ws_size,
                              hipStream_t stream) {
    (void)in_sizes; (void)n_in; (void)out_size; (void)ws_size;
    const float* X = (const float*)d_in[0];
    float* out = (float*)d_out;
    char* ws = (char*)d_ws;
    u16*   Xt = (u16*)(ws + OFF_XT);
    float* s  = (float*)(ws + OFF_S);
    float* F  = (float*)(ws + OFF_F);
    float* dv = (float*)(ws + OFF_D);
    float* rv = (float*)(ws + OFF_R);
    float* dd = (float*)(ws + OFF_DD);
    float* rd = (float*)(ws + OFF_RD);
    float* tb = (float*)(ws + OFF_T);

    hipMemsetAsync(ws + OFF_S, 0, ZERO_BYTES, stream);     // zero s + F

    hipLaunchKernelGGL(k_transpose, dim3(64, 8, 6), dim3(256), 0, stream, X, Xt, s);
    hipLaunchKernelGGL(k_rowstats,  dim3(6144),     dim3(256), 0, stream, X, s, dv, rv);
    hipLaunchKernelGGL(k_pairdots,  dim3(NPAIR),    dim3(256), 0, stream, dv, rv, s, dd, rd, tb);
    hipLaunchKernelGGL(k_gemm_frob, dim3(8, NPAIR, KSPLIT), dim3(256), 0, stream, Xt, F);
    hipLaunchKernelGGL(k_finalize,  dim3(1),        dim3(64),  0, stream, F, dd, rd, tb, out);
}